// Round 3
// baseline (833.150 us; speedup 1.0000x reference)
//
#include <hip/hip_runtime.h>
#include <math.h>

#define NTN 32768      // total nodes
#define NBG 32         // batch (graphs)
#define NN  1024       // nodes per graph
#define EE  262144     // edges
#define FIN 64
#define HIDC 128
#define HD  4
#define HC  512        // HD*HIDC
#define EDIM 16
#define NR  16
#define KP1 820
#define KP2 656
#define NEGS 0.2f
#define NPB 8          // dst nodes per gat block
#define CHUNK 64       // max edges buffered per wave

// ---------------- fused node GEMM: Cl/Cr = (A*gate) @ Wl/Wr + bl/br ----------------
template<int K>
__global__ __launch_bounds__(256) void gemm_node2(const float* __restrict__ A,
                                                  const float* __restrict__ Wl,
                                                  const float* __restrict__ bl,
                                                  const float* __restrict__ Wr,
                                                  const float* __restrict__ br,
                                                  const float* __restrict__ gs,
                                                  float* __restrict__ Cl,
                                                  float* __restrict__ Cr) {
    __shared__ float a_s[K][16];
    __shared__ float g_s[16];
    int t = threadIdx.x;
    int row0 = blockIdx.x * 16;
    if (t < 16) g_s[t] = gs ? tanhf(gs[row0 + t]) : 1.0f;
    __syncthreads();
    for (int i = t; i < 16 * K; i += 256) {
        int r = i / K, k = i % K;
        a_s[k][r] = A[(size_t)(row0 + r) * K + k] * g_s[r];
    }
    __syncthreads();
    int c0 = t, c1 = t + 256;
    float accl0[16], accl1[16], accr0[16], accr1[16];
    float bl0 = bl[c0], bl1 = bl[c1], br0 = br[c0], br1 = br[c1];
    #pragma unroll
    for (int r = 0; r < 16; r++) { accl0[r] = bl0; accl1[r] = bl1; accr0[r] = br0; accr1[r] = br1; }
    for (int k = 0; k < K; k++) {
        float wl0 = Wl[(size_t)k * HC + c0], wl1 = Wl[(size_t)k * HC + c1];
        float wr0 = Wr[(size_t)k * HC + c0], wr1 = Wr[(size_t)k * HC + c1];
        const float4* ap = (const float4*)&a_s[k][0];
        float4 A0 = ap[0], A1 = ap[1], A2 = ap[2], A3 = ap[3];
        float av[16] = {A0.x, A0.y, A0.z, A0.w, A1.x, A1.y, A1.z, A1.w,
                        A2.x, A2.y, A2.z, A2.w, A3.x, A3.y, A3.z, A3.w};
        #pragma unroll
        for (int r = 0; r < 16; r++) {
            accl0[r] += av[r] * wl0; accl1[r] += av[r] * wl1;
            accr0[r] += av[r] * wr0; accr1[r] += av[r] * wr1;
        }
    }
    for (int r = 0; r < 16; r++) {
        Cl[(size_t)(row0 + r) * HC + c0] = accl0[r];
        Cl[(size_t)(row0 + r) * HC + c1] = accl1[r];
        Cr[(size_t)(row0 + r) * HC + c0] = accr0[r];
        Cr[(size_t)(row0 + r) * HC + c1] = accr1[r];
    }
}

// ---------------- edge CSR build (optionally keep-filtered), permuted edge_attr ----------------
__global__ void edge_hist(const int* __restrict__ dst, const int* __restrict__ src,
                          const int* __restrict__ keep, int* __restrict__ deg) {
    int e = blockIdx.x * 256 + threadIdx.x;
    if (e < EE) {
        if (keep && (!keep[src[e]] || !keep[dst[e]])) return;
        atomicAdd(&deg[dst[e]], 1);
    }
}

__global__ __launch_bounds__(1024) void scan_deg(const int* __restrict__ deg,
                                                 int* __restrict__ off, int* __restrict__ cur) {
    __shared__ int s[1024];
    int t = threadIdx.x;
    int base = t * 32;
    int local[32];
    int sum = 0;
    #pragma unroll
    for (int i = 0; i < 32; i++) { local[i] = deg[base + i]; sum += local[i]; }
    s[t] = sum;
    for (int o = 1; o < 1024; o <<= 1) {
        __syncthreads();
        int v = (t >= o) ? s[t - o] : 0;
        __syncthreads();
        s[t] += v;
    }
    __syncthreads();
    int run = s[t] - sum;  // exclusive prefix of this chunk
    #pragma unroll
    for (int i = 0; i < 32; i++) { off[base + i] = run; cur[base + i] = run; run += local[i]; }
    if (t == 1023) off[NTN] = s[1023];
}

__global__ void edge_scatter(const int* __restrict__ dst, const int* __restrict__ src,
                             const int* __restrict__ keep, const float* __restrict__ ea,
                             int* __restrict__ cur,
                             int* __restrict__ esrc, float* __restrict__ eaP) {
    int e = blockIdx.x * 256 + threadIdx.x;
    if (e < EE) {
        if (keep && (!keep[src[e]] || !keep[dst[e]])) return;
        int p = atomicAdd(&cur[dst[e]], 1);
        esrc[p] = src[e];
        const float4* s4 = (const float4*)(ea + (size_t)e * EDIM);
        float4* d4 = (float4*)(eaP + (size_t)p * EDIM);
        d4[0] = s4[0]; d4[1] = s4[1]; d4[2] = s4[2]; d4[3] = s4[3];
    }
}

// ---------------- fused GATv2: wave-per-head, chunked two-pass softmax, fused score ----------------
__global__ __launch_bounds__(256) void gat_dst(
        const float* __restrict__ xl, const float* __restrict__ xr,
        const float* __restrict__ eaP, const float* __restrict__ We,
        const float* __restrict__ att, const float* __restrict__ bias,
        const float* __restrict__ pvec,
        const int* __restrict__ esrc, const int* __restrict__ off,
        float* __restrict__ out, float* __restrict__ score) {
    int t = threadIdx.x;
    int w = t >> 6, lane = t & 63;
    int c = w * HIDC + lane * 2;         // 2 channels of head w
    __shared__ float logitS[HD][CHUNK];
    __shared__ int   srcS[HD][CHUNK];
    __shared__ float red[2][HC];
    __shared__ float red2[2][HIDC];
    __shared__ float biasS[HIDC], pS[HIDC];
    __shared__ float invn_s;
    float we0[EDIM], we1[EDIM];
    #pragma unroll
    for (int k = 0; k < EDIM; k++) {
        we0[k] = We[(size_t)k * HC + c];
        we1[k] = We[(size_t)k * HC + c + 1];
    }
    float at0 = att[c], at1 = att[c + 1];
    if (t < HIDC) { biasS[t] = bias[t]; pS[t] = pvec[t]; }
    __syncthreads();
    if (t < 64) {
        float s = pS[t] * pS[t] + pS[t + 64] * pS[t + 64];
        #pragma unroll
        for (int sft = 32; sft; sft >>= 1) s += __shfl_xor(s, sft, 64);
        if (t == 0) invn_s = 1.f / (sqrtf(s) + 1e-16f);
    }
    __syncthreads();
    float invn = invn_s;

    for (int n = 0; n < NPB; n++) {
        int d = blockIdx.x * NPB + n;
        float2 xrv = *(const float2*)&xr[((unsigned)d << 9) + c];
        int e0 = off[d], e1 = off[d + 1];
        float m = -3e38f, den = 0.f, acc0 = 0.f, acc1 = 0.f;
        for (int cb = e0; cb < e1; cb += CHUNK) {
            int ce = cb + CHUNK < e1 ? cb + CHUNK : e1;
            float mx = -3e38f;
            // pass 1: logits (independent iterations)
            for (int ei = cb; ei < ce; ei++) {
                const float4* eap = (const float4*)(eaP + ((size_t)ei << 4));
                float4 E0 = eap[0], E1 = eap[1], E2 = eap[2], E3 = eap[3];
                int s = esrc[ei];
                float2 xlv = *(const float2*)&xl[((unsigned)s << 9) + c];
                float ev[16] = {E0.x, E0.y, E0.z, E0.w, E1.x, E1.y, E1.z, E1.w,
                                E2.x, E2.y, E2.z, E2.w, E3.x, E3.y, E3.z, E3.w};
                float ef0 = 0.f, ef1 = 0.f;
                #pragma unroll
                for (int k = 0; k < EDIM; k++) { ef0 += ev[k] * we0[k]; ef1 += ev[k] * we1[k]; }
                float v0 = xlv.x + xrv.x + ef0; v0 = v0 > 0.f ? v0 : NEGS * v0;
                float v1 = xlv.y + xrv.y + ef1; v1 = v1 > 0.f ? v1 : NEGS * v1;
                float p = v0 * at0 + v1 * at1;
                #pragma unroll
                for (int sft = 32; sft; sft >>= 1) p += __shfl_xor(p, sft, 64);
                if (lane == 0) { logitS[w][ei - cb] = p; srcS[w][ei - cb] = s; }
                mx = fmaxf(mx, p);
            }
            // merge chunk max into running state (once per chunk)
            float nm = fmaxf(m, mx);
            float sc = __expf(m - nm);
            den *= sc; acc0 *= sc; acc1 *= sc; m = nm;
            // pass 2: weights + accumulate (independent iterations)
            for (int ei = cb; ei < ce; ei++) {
                float l = logitS[w][ei - cb];
                int s = srcS[w][ei - cb];
                float wt = __expf(l - m);
                float2 xlv = *(const float2*)&xl[((unsigned)s << 9) + c];
                den += wt;
                acc0 += wt * xlv.x;
                acc1 += wt * xlv.y;
            }
        }
        int buf = n & 1;
        float inv = 1.f / (den + 1e-16f);
        red[buf][c] = acc0 * inv;
        red[buf][c + 1] = acc1 * inv;
        __syncthreads();
        if (t < HIDC) {
            float v = (red[buf][t] + red[buf][t + 128] + red[buf][t + 256] + red[buf][t + 384]) * 0.25f + biasS[t];
            v = fmaxf(v, 0.f);
            out[((unsigned)d << 7) + t] = v;
            red2[buf][t] = v * pS[t];
        }
        __syncthreads();
        if (t < 64) {
            float sv = red2[buf][t] + red2[buf][t + 64];
            #pragma unroll
            for (int sft = 32; sft; sft >>= 1) sv += __shfl_xor(sv, sft, 64);
            if (t == 0) score[d] = sv * invn;
        }
    }
}

// ---------------- top-k ----------------
__global__ __launch_bounds__(512) void topk_sel(const float* __restrict__ score,
                                                const int* __restrict__ mask, int k,
                                                int* __restrict__ keep) {
    __shared__ float v[NN];
    __shared__ short id[NN];
    int g = blockIdx.x, t = threadIdx.x;
    for (int i = t; i < NN; i += 512) {
        int n = g * NN + i;
        bool mk = mask ? (mask[n] != 0) : true;
        v[i] = mk ? score[n] : -INFINITY;
        id[i] = (short)i;
    }
    __syncthreads();
    for (int kk = 2; kk <= NN; kk <<= 1) {
        for (int j = kk >> 1; j > 0; j >>= 1) {
            #pragma unroll 2
            for (int i = t; i < NN; i += 512) {
                int ixj = i ^ j;
                if (ixj > i) {
                    bool up = ((i & kk) == 0);
                    float a = v[i], b2 = v[ixj];
                    short ia = id[i], ib = id[ixj];
                    bool aFirst = (a > b2) || (a == b2 && ia < ib);
                    if (up ? !aFirst : aFirst) { v[i] = b2; v[ixj] = a; id[i] = ib; id[ixj] = ia; }
                }
            }
            __syncthreads();
        }
    }
    for (int i = t; i < NN; i += 512) keep[g * NN + id[i]] = (i < k) ? 1 : 0;
}

// ---------------- global pool (gate fused) + MLP ----------------
__global__ __launch_bounds__(512) void gpool(const float* __restrict__ h,
                                             const int* __restrict__ keep,
                                             const float* __restrict__ score,
                                             const float* __restrict__ action,
                                             float* __restrict__ z) {
    int g = blockIdx.x, t = threadIdx.x;
    int c = t & 127, ch = t >> 7;    // 4 chunks of 256 nodes
    __shared__ float gt_s[NN];
    __shared__ char kp_s[NN];
    __shared__ float smx[4][HIDC], ssm[4][HIDC];
    for (int i = t; i < NN; i += 512) {
        int n = g * NN + i;
        int kk = keep[n];
        kp_s[i] = (char)kk;
        gt_s[i] = kk ? tanhf(score[n]) : 0.f;
    }
    __syncthreads();
    float mx = -INFINITY, sm = 0.f;
    for (int n = ch * 256; n < ch * 256 + 256; n++) {
        if (kp_s[n]) {
            float v = h[(size_t)(g * NN + n) * HIDC + c] * gt_s[n];
            mx = fmaxf(mx, v);
            sm += v;
        }
    }
    smx[ch][c] = mx; ssm[ch][c] = sm;
    __syncthreads();
    if (t < HIDC) {
        mx = fmaxf(fmaxf(smx[0][t], smx[1][t]), fmaxf(smx[2][t], smx[3][t]));
        sm = ssm[0][t] + ssm[1][t] + ssm[2][t] + ssm[3][t];
        z[g * 272 + t] = mx;
        z[g * 272 + 128 + t] = sm / (float)KP2;
        if (t < NR) z[g * 272 + 256 + t] = action[g * NR + t];
    }
}

__global__ __launch_bounds__(128) void mlp(const float* __restrict__ z,
                                           const float* __restrict__ Wf1, const float* __restrict__ bf1,
                                           const float* __restrict__ Wf2, const float* __restrict__ bf2,
                                           const float* __restrict__ Wf3, const float* __restrict__ bf3,
                                           float* __restrict__ out) {
    int g = blockIdx.x, t = threadIdx.x;
    __shared__ float zs[272], z1[HIDC], z2[HIDC], r[HIDC];
    for (int i = t; i < 272; i += 128) zs[i] = z[g * 272 + i];
    __syncthreads();
    float a = bf1[t];
    for (int k = 0; k < 272; k++) a += zs[k] * Wf1[(size_t)k * HIDC + t];
    z1[t] = fmaxf(a, 0.f);
    __syncthreads();
    a = bf2[t];
    for (int k = 0; k < HIDC; k++) a += z1[k] * Wf2[(size_t)k * HIDC + t];
    z2[t] = fmaxf(a, 0.f);
    __syncthreads();
    r[t] = z2[t] * Wf3[t];
    __syncthreads();
    for (int s = 64; s; s >>= 1) { if (t < s) r[t] += r[t + s]; __syncthreads(); }
    if (t == 0) out[g] = r[0] + bf3[0];
}

extern "C" void kernel_launch(void* const* d_in, const int* in_sizes, int n_in,
                              void* d_out, int out_size, void* d_ws, size_t ws_size,
                              hipStream_t stream) {
    const float* x    = (const float*)d_in[0];
    const float* ea   = (const float*)d_in[1];
    const float* act  = (const float*)d_in[2];
    const float* W1l  = (const float*)d_in[3];
    const float* b1l  = (const float*)d_in[4];
    const float* W1r  = (const float*)d_in[5];
    const float* b1r  = (const float*)d_in[6];
    const float* W1e  = (const float*)d_in[7];
    const float* att1 = (const float*)d_in[8];
    const float* bias1= (const float*)d_in[9];
    const float* W2l  = (const float*)d_in[10];
    const float* b2l  = (const float*)d_in[11];
    const float* W2r  = (const float*)d_in[12];
    const float* b2r  = (const float*)d_in[13];
    const float* W2e  = (const float*)d_in[14];
    const float* att2 = (const float*)d_in[15];
    const float* bias2= (const float*)d_in[16];
    const float* p1   = (const float*)d_in[17];
    const float* p2   = (const float*)d_in[18];
    const float* Wf1  = (const float*)d_in[19];
    const float* bf1  = (const float*)d_in[20];
    const float* Wf2  = (const float*)d_in[21];
    const float* bf2  = (const float*)d_in[22];
    const float* Wf3  = (const float*)d_in[23];
    const float* bf3  = (const float*)d_in[24];
    const int*   eix  = (const int*)d_in[25];
    const int* srcA = eix;
    const int* dstA = eix + EE;

    float* ws    = (float*)d_ws;
    float* xl    = ws;
    float* xr    = xl + (size_t)NTN * HC;
    float* h     = xr + (size_t)NTN * HC;
    float* score1= h + (size_t)NTN * HIDC;
    float* score2= score1 + NTN;
    float* zbuf  = score2 + NTN;
    int* keep1 = (int*)(zbuf + NBG * 272);
    int* keep2 = keep1 + NTN;
    int* deg   = keep2 + NTN;
    int* off   = deg + NTN;
    int* cur   = off + NTN + 1;
    int* deg2  = cur + NTN;
    int* off2  = deg2 + NTN;
    int* cur2  = off2 + NTN + 1;
    int* esrc  = cur2 + NTN;
    int* esrc2 = esrc + EE;
    float* eaP  = (float*)(esrc2 + EE);
    float* eaP2 = eaP + (size_t)EE * EDIM;

    // ---- CSR layer 1 (all edges) ----
    hipMemsetAsync(deg, 0, NTN * sizeof(int), stream);
    edge_hist<<<EE / 256, 256, 0, stream>>>(dstA, srcA, nullptr, deg);
    scan_deg<<<1, 1024, 0, stream>>>(deg, off, cur);
    edge_scatter<<<EE / 256, 256, 0, stream>>>(dstA, srcA, nullptr, ea, cur, esrc, eaP);

    // ---- layer 1 ----
    gemm_node2<FIN><<<NTN / 16, 256, 0, stream>>>(x, W1l, b1l, W1r, b1r, nullptr, xl, xr);
    gat_dst<<<NTN / NPB, 256, 0, stream>>>(xl, xr, eaP, W1e, att1, bias1, p1, esrc, off, h, score1);

    // ---- pool 1 ----
    topk_sel<<<NBG, 512, 0, stream>>>(score1, nullptr, KP1, keep1);

    // ---- CSR layer 2 (live edges only) ----
    hipMemsetAsync(deg2, 0, NTN * sizeof(int), stream);
    edge_hist<<<EE / 256, 256, 0, stream>>>(dstA, srcA, keep1, deg2);
    scan_deg<<<1, 1024, 0, stream>>>(deg2, off2, cur2);
    edge_scatter<<<EE / 256, 256, 0, stream>>>(dstA, srcA, keep1, ea, cur2, esrc2, eaP2);

    // ---- layer 2 (gate of pool1 fused into GEMM staging) ----
    gemm_node2<HIDC><<<NTN / 16, 256, 0, stream>>>(h, W2l, b2l, W2r, b2r, score1, xl, xr);
    gat_dst<<<NTN / NPB, 256, 0, stream>>>(xl, xr, eaP2, W2e, att2, bias2, p2, esrc2, off2, h, score2);

    // ---- pool 2 ----
    topk_sel<<<NBG, 512, 0, stream>>>(score2, keep1, KP2, keep2);

    // ---- global pool (gate2 fused) + MLP ----
    gpool<<<NBG, 512, 0, stream>>>(h, keep2, score2, act, zbuf);
    mlp<<<NBG, 128, 0, stream>>>(zbuf, Wf1, bf1, Wf2, bf2, Wf3, bf3, (float*)d_out);
}

// Round 4
// 635.413 us; speedup vs baseline: 1.3112x; 1.3112x over previous
//
#include <hip/hip_runtime.h>
#include <math.h>

#define NTN 32768      // total nodes
#define NBG 32         // batch (graphs)
#define NN  1024       // nodes per graph
#define EE  262144     // edges
#define FIN 64
#define HIDC 128
#define HD  4
#define HC  512        // HD*HIDC
#define EDIM 16
#define NR  16
#define KP1 820
#define KP2 656
#define NEGS 0.2f
#define NPB 2          // dst nodes per gat block

// ---------------- fused node GEMM: Cl/Cr = (A*gate) @ Wl/Wr + bl/br ----------------
template<int K>
__global__ __launch_bounds__(256) void gemm_node2(const float* __restrict__ A,
                                                  const float* __restrict__ Wl,
                                                  const float* __restrict__ bl,
                                                  const float* __restrict__ Wr,
                                                  const float* __restrict__ br,
                                                  const float* __restrict__ gs,
                                                  float* __restrict__ Cl,
                                                  float* __restrict__ Cr) {
    __shared__ float a_s[K][16];
    __shared__ float g_s[16];
    int t = threadIdx.x;
    int row0 = blockIdx.x * 16;
    if (t < 16) g_s[t] = gs ? tanhf(gs[row0 + t]) : 1.0f;
    __syncthreads();
    for (int i = t; i < 16 * K; i += 256) {
        int r = i / K, k = i % K;
        a_s[k][r] = A[(size_t)(row0 + r) * K + k] * g_s[r];
    }
    __syncthreads();
    int c0 = t, c1 = t + 256;
    float accl0[16], accl1[16], accr0[16], accr1[16];
    float bl0 = bl[c0], bl1 = bl[c1], br0 = br[c0], br1 = br[c1];
    #pragma unroll
    for (int r = 0; r < 16; r++) { accl0[r] = bl0; accl1[r] = bl1; accr0[r] = br0; accr1[r] = br1; }
    for (int k = 0; k < K; k++) {
        float wl0 = Wl[(size_t)k * HC + c0], wl1 = Wl[(size_t)k * HC + c1];
        float wr0 = Wr[(size_t)k * HC + c0], wr1 = Wr[(size_t)k * HC + c1];
        const float4* ap = (const float4*)&a_s[k][0];
        float4 A0 = ap[0], A1 = ap[1], A2 = ap[2], A3 = ap[3];
        float av[16] = {A0.x, A0.y, A0.z, A0.w, A1.x, A1.y, A1.z, A1.w,
                        A2.x, A2.y, A2.z, A2.w, A3.x, A3.y, A3.z, A3.w};
        #pragma unroll
        for (int r = 0; r < 16; r++) {
            accl0[r] += av[r] * wl0; accl1[r] += av[r] * wl1;
            accr0[r] += av[r] * wr0; accr1[r] += av[r] * wr1;
        }
    }
    for (int r = 0; r < 16; r++) {
        Cl[(size_t)(row0 + r) * HC + c0] = accl0[r];
        Cl[(size_t)(row0 + r) * HC + c1] = accl1[r];
        Cr[(size_t)(row0 + r) * HC + c0] = accr0[r];
        Cr[(size_t)(row0 + r) * HC + c1] = accr1[r];
    }
}

// ---------------- edge CSR build (optionally keep-filtered), permuted edge_attr ----------------
__global__ void edge_hist(const int* __restrict__ dst, const int* __restrict__ src,
                          const int* __restrict__ keep, int* __restrict__ deg) {
    int e = blockIdx.x * 256 + threadIdx.x;
    if (e < EE) {
        if (keep && (!keep[src[e]] || !keep[dst[e]])) return;
        atomicAdd(&deg[dst[e]], 1);
    }
}

__global__ __launch_bounds__(1024) void scan_deg(const int* __restrict__ deg,
                                                 int* __restrict__ off, int* __restrict__ cur) {
    __shared__ int s[1024];
    int t = threadIdx.x;
    int base = t * 32;
    int local[32];
    int sum = 0;
    #pragma unroll
    for (int i = 0; i < 32; i++) { local[i] = deg[base + i]; sum += local[i]; }
    s[t] = sum;
    for (int o = 1; o < 1024; o <<= 1) {
        __syncthreads();
        int v = (t >= o) ? s[t - o] : 0;
        __syncthreads();
        s[t] += v;
    }
    __syncthreads();
    int run = s[t] - sum;  // exclusive prefix of this chunk
    #pragma unroll
    for (int i = 0; i < 32; i++) { off[base + i] = run; cur[base + i] = run; run += local[i]; }
    if (t == 1023) off[NTN] = s[1023];
}

__global__ void edge_scatter(const int* __restrict__ dst, const int* __restrict__ src,
                             const int* __restrict__ keep, const float* __restrict__ ea,
                             int* __restrict__ cur,
                             int* __restrict__ esrc, float* __restrict__ eaP) {
    int e = blockIdx.x * 256 + threadIdx.x;
    if (e < EE) {
        if (keep && (!keep[src[e]] || !keep[dst[e]])) return;
        int p = atomicAdd(&cur[dst[e]], 1);
        esrc[p] = src[e];
        const float4* s4 = (const float4*)(ea + (size_t)e * EDIM);
        float4* d4 = (float4*)(eaP + (size_t)p * EDIM);
        d4[0] = s4[0]; d4[1] = s4[1]; d4[2] = s4[2]; d4[3] = s4[3];
    }
}

// ---------------- p-norm inverse (once per layer) ----------------
__global__ __launch_bounds__(64) void prep_pn(const float* __restrict__ p1,
                                              const float* __restrict__ p2,
                                              float* __restrict__ pn) {
    int t = threadIdx.x;
    float a = p1[t] * p1[t] + p1[t + 64] * p1[t + 64];
    float b = p2[t] * p2[t] + p2[t + 64] * p2[t + 64];
    #pragma unroll
    for (int sft = 32; sft; sft >>= 1) { a += __shfl_xor(a, sft, 64); b += __shfl_xor(b, sft, 64); }
    if (t == 0) { pn[0] = 1.f / (sqrtf(a) + 1e-16f); pn[1] = 1.f / (sqrtf(b) + 1e-16f); }
}

// ---------------- fused GATv2: wave-per-head, single-pass defer-max softmax, fused score ----------------
__global__ __launch_bounds__(256) void gat_dst(
        const float* __restrict__ xl, const float* __restrict__ xr,
        const float* __restrict__ eaP, const float* __restrict__ We,
        const float* __restrict__ att, const float* __restrict__ bias,
        const float* __restrict__ pvec, const float* __restrict__ pnInv,
        const int* __restrict__ esrc, const int* __restrict__ off,
        float* __restrict__ out, float* __restrict__ score) {
    int t = threadIdx.x;
    int w = t >> 6, lane = t & 63;
    int c = w * HIDC + lane * 2;         // 2 channels of head w
    __shared__ float red[NPB][HC];
    __shared__ float red2[NPB][HIDC];
    float we0[EDIM], we1[EDIM];
    #pragma unroll
    for (int k = 0; k < EDIM; k++) {
        we0[k] = We[(size_t)k * HC + c];
        we1[k] = We[(size_t)k * HC + c + 1];
    }
    float at0 = att[c], at1 = att[c + 1];
    int d0 = blockIdx.x * NPB;

    for (int n = 0; n < NPB; n++) {
        int d = d0 + n;
        float2 xrv = *(const float2*)&xr[((unsigned)d << 9) + c];
        int e0 = off[d], e1 = off[d + 1];
        float m = -3e38f, den = 0.f, acc0 = 0.f, acc1 = 0.f;
        int ei = e0;
        for (; ei + 2 <= e1; ei += 2) {
            int sA = esrc[ei], sB = esrc[ei + 1];
            const float4* eA = (const float4*)(eaP + ((size_t)ei << 4));
            float4 A0 = eA[0], A1 = eA[1], A2 = eA[2], A3 = eA[3];
            float4 B0 = eA[4], B1 = eA[5], B2 = eA[6], B3 = eA[7];
            float2 xlA = *(const float2*)&xl[((unsigned)sA << 9) + c];
            float2 xlB = *(const float2*)&xl[((unsigned)sB << 9) + c];
            float avA[16] = {A0.x, A0.y, A0.z, A0.w, A1.x, A1.y, A1.z, A1.w,
                             A2.x, A2.y, A2.z, A2.w, A3.x, A3.y, A3.z, A3.w};
            float avB[16] = {B0.x, B0.y, B0.z, B0.w, B1.x, B1.y, B1.z, B1.w,
                             B2.x, B2.y, B2.z, B2.w, B3.x, B3.y, B3.z, B3.w};
            float efA0 = 0.f, efA1 = 0.f, efB0 = 0.f, efB1 = 0.f;
            #pragma unroll
            for (int k = 0; k < EDIM; k++) {
                efA0 += avA[k] * we0[k]; efA1 += avA[k] * we1[k];
                efB0 += avB[k] * we0[k]; efB1 += avB[k] * we1[k];
            }
            float vA0 = xlA.x + xrv.x + efA0; vA0 = vA0 > 0.f ? vA0 : NEGS * vA0;
            float vA1 = xlA.y + xrv.y + efA1; vA1 = vA1 > 0.f ? vA1 : NEGS * vA1;
            float vB0 = xlB.x + xrv.x + efB0; vB0 = vB0 > 0.f ? vB0 : NEGS * vB0;
            float vB1 = xlB.y + xrv.y + efB1; vB1 = vB1 > 0.f ? vB1 : NEGS * vB1;
            float pA = vA0 * at0 + vA1 * at1;
            float pB = vB0 * at0 + vB1 * at1;
            #pragma unroll
            for (int sft = 32; sft; sft >>= 1) {
                pA += __shfl_xor(pA, sft, 64);
                pB += __shfl_xor(pB, sft, 64);
            }
            if (pA > m + 8.f) {       // rare after first edge (logit spread << 8)
                float sc = __expf(m - pA);
                den = den * sc + 1.f; acc0 = acc0 * sc + xlA.x; acc1 = acc1 * sc + xlA.y;
                m = pA;
            } else {
                float wt = __expf(pA - m);
                den += wt; acc0 += wt * xlA.x; acc1 += wt * xlA.y;
            }
            if (pB > m + 8.f) {
                float sc = __expf(m - pB);
                den = den * sc + 1.f; acc0 = acc0 * sc + xlB.x; acc1 = acc1 * sc + xlB.y;
                m = pB;
            } else {
                float wt = __expf(pB - m);
                den += wt; acc0 += wt * xlB.x; acc1 += wt * xlB.y;
            }
        }
        if (ei < e1) {
            int s = esrc[ei];
            const float4* eA = (const float4*)(eaP + ((size_t)ei << 4));
            float4 A0 = eA[0], A1 = eA[1], A2 = eA[2], A3 = eA[3];
            float2 xlA = *(const float2*)&xl[((unsigned)s << 9) + c];
            float avA[16] = {A0.x, A0.y, A0.z, A0.w, A1.x, A1.y, A1.z, A1.w,
                             A2.x, A2.y, A2.z, A2.w, A3.x, A3.y, A3.z, A3.w};
            float ef0 = 0.f, ef1 = 0.f;
            #pragma unroll
            for (int k = 0; k < EDIM; k++) { ef0 += avA[k] * we0[k]; ef1 += avA[k] * we1[k]; }
            float v0 = xlA.x + xrv.x + ef0; v0 = v0 > 0.f ? v0 : NEGS * v0;
            float v1 = xlA.y + xrv.y + ef1; v1 = v1 > 0.f ? v1 : NEGS * v1;
            float p = v0 * at0 + v1 * at1;
            #pragma unroll
            for (int sft = 32; sft; sft >>= 1) p += __shfl_xor(p, sft, 64);
            if (p > m + 8.f) {
                float sc = __expf(m - p);
                den = den * sc + 1.f; acc0 = acc0 * sc + xlA.x; acc1 = acc1 * sc + xlA.y;
                m = p;
            } else {
                float wt = __expf(p - m);
                den += wt; acc0 += wt * xlA.x; acc1 += wt * xlA.y;
            }
        }
        float inv = 1.f / (den + 1e-16f);
        red[n][c] = acc0 * inv;
        red[n][c + 1] = acc1 * inv;
    }
    __syncthreads();
    // epilogue: thread t handles node (t>>7), channel (t&127)
    {
        int n2 = t >> 7, tc = t & 127;
        float v = (red[n2][tc] + red[n2][tc + 128] + red[n2][tc + 256] + red[n2][tc + 384]) * 0.25f
                  + bias[tc];
        v = fmaxf(v, 0.f);
        out[((unsigned)(d0 + n2) << 7) + tc] = v;
        red2[n2][tc] = v * pvec[tc];
    }
    __syncthreads();
    if (t < 128) {
        int n3 = t >> 6, l2 = t & 63;
        float sv = red2[n3][l2] + red2[n3][l2 + 64];
        #pragma unroll
        for (int sft = 32; sft; sft >>= 1) sv += __shfl_xor(sv, sft, 64);
        if (l2 == 0) score[d0 + n3] = sv * pnInv[0];
    }
}

// ---------------- top-k ----------------
__global__ __launch_bounds__(512) void topk_sel(const float* __restrict__ score,
                                                const int* __restrict__ mask, int k,
                                                int* __restrict__ keep) {
    __shared__ float v[NN];
    __shared__ short id[NN];
    int g = blockIdx.x, t = threadIdx.x;
    for (int i = t; i < NN; i += 512) {
        int n = g * NN + i;
        bool mk = mask ? (mask[n] != 0) : true;
        v[i] = mk ? score[n] : -INFINITY;
        id[i] = (short)i;
    }
    __syncthreads();
    for (int kk = 2; kk <= NN; kk <<= 1) {
        for (int j = kk >> 1; j > 0; j >>= 1) {
            #pragma unroll 2
            for (int i = t; i < NN; i += 512) {
                int ixj = i ^ j;
                if (ixj > i) {
                    bool up = ((i & kk) == 0);
                    float a = v[i], b2 = v[ixj];
                    short ia = id[i], ib = id[ixj];
                    bool aFirst = (a > b2) || (a == b2 && ia < ib);
                    if (up ? !aFirst : aFirst) { v[i] = b2; v[ixj] = a; id[i] = ib; id[ixj] = ia; }
                }
            }
            __syncthreads();
        }
    }
    for (int i = t; i < NN; i += 512) keep[g * NN + id[i]] = (i < k) ? 1 : 0;
}

// ---------------- global pool (gate fused) + MLP ----------------
__global__ __launch_bounds__(512) void gpool(const float* __restrict__ h,
                                             const int* __restrict__ keep,
                                             const float* __restrict__ score,
                                             const float* __restrict__ action,
                                             float* __restrict__ z) {
    int g = blockIdx.x, t = threadIdx.x;
    int c = t & 127, ch = t >> 7;    // 4 chunks of 256 nodes
    __shared__ float gt_s[NN];
    __shared__ char kp_s[NN];
    __shared__ float smx[4][HIDC], ssm[4][HIDC];
    for (int i = t; i < NN; i += 512) {
        int n = g * NN + i;
        int kk = keep[n];
        kp_s[i] = (char)kk;
        gt_s[i] = kk ? tanhf(score[n]) : 0.f;
    }
    __syncthreads();
    float mx = -INFINITY, sm = 0.f;
    for (int n = ch * 256; n < ch * 256 + 256; n++) {
        if (kp_s[n]) {
            float v = h[(size_t)(g * NN + n) * HIDC + c] * gt_s[n];
            mx = fmaxf(mx, v);
            sm += v;
        }
    }
    smx[ch][c] = mx; ssm[ch][c] = sm;
    __syncthreads();
    if (t < HIDC) {
        mx = fmaxf(fmaxf(smx[0][t], smx[1][t]), fmaxf(smx[2][t], smx[3][t]));
        sm = ssm[0][t] + ssm[1][t] + ssm[2][t] + ssm[3][t];
        z[g * 272 + t] = mx;
        z[g * 272 + 128 + t] = sm / (float)KP2;
        if (t < NR) z[g * 272 + 256 + t] = action[g * NR + t];
    }
}

__global__ __launch_bounds__(128) void mlp(const float* __restrict__ z,
                                           const float* __restrict__ Wf1, const float* __restrict__ bf1,
                                           const float* __restrict__ Wf2, const float* __restrict__ bf2,
                                           const float* __restrict__ Wf3, const float* __restrict__ bf3,
                                           float* __restrict__ out) {
    int g = blockIdx.x, t = threadIdx.x;
    __shared__ float zs[272], z1[HIDC], z2[HIDC], r[HIDC];
    for (int i = t; i < 272; i += 128) zs[i] = z[g * 272 + i];
    __syncthreads();
    float a = bf1[t];
    for (int k = 0; k < 272; k++) a += zs[k] * Wf1[(size_t)k * HIDC + t];
    z1[t] = fmaxf(a, 0.f);
    __syncthreads();
    a = bf2[t];
    for (int k = 0; k < HIDC; k++) a += z1[k] * Wf2[(size_t)k * HIDC + t];
    z2[t] = fmaxf(a, 0.f);
    __syncthreads();
    r[t] = z2[t] * Wf3[t];
    __syncthreads();
    for (int s = 64; s; s >>= 1) { if (t < s) r[t] += r[t + s]; __syncthreads(); }
    if (t == 0) out[g] = r[0] + bf3[0];
}

extern "C" void kernel_launch(void* const* d_in, const int* in_sizes, int n_in,
                              void* d_out, int out_size, void* d_ws, size_t ws_size,
                              hipStream_t stream) {
    const float* x    = (const float*)d_in[0];
    const float* ea   = (const float*)d_in[1];
    const float* act  = (const float*)d_in[2];
    const float* W1l  = (const float*)d_in[3];
    const float* b1l  = (const float*)d_in[4];
    const float* W1r  = (const float*)d_in[5];
    const float* b1r  = (const float*)d_in[6];
    const float* W1e  = (const float*)d_in[7];
    const float* att1 = (const float*)d_in[8];
    const float* bias1= (const float*)d_in[9];
    const float* W2l  = (const float*)d_in[10];
    const float* b2l  = (const float*)d_in[11];
    const float* W2r  = (const float*)d_in[12];
    const float* b2r  = (const float*)d_in[13];
    const float* W2e  = (const float*)d_in[14];
    const float* att2 = (const float*)d_in[15];
    const float* bias2= (const float*)d_in[16];
    const float* p1   = (const float*)d_in[17];
    const float* p2   = (const float*)d_in[18];
    const float* Wf1  = (const float*)d_in[19];
    const float* bf1  = (const float*)d_in[20];
    const float* Wf2  = (const float*)d_in[21];
    const float* bf2  = (const float*)d_in[22];
    const float* Wf3  = (const float*)d_in[23];
    const float* bf3  = (const float*)d_in[24];
    const int*   eix  = (const int*)d_in[25];
    const int* srcA = eix;
    const int* dstA = eix + EE;

    float* ws    = (float*)d_ws;
    float* xl    = ws;
    float* xr    = xl + (size_t)NTN * HC;
    float* h     = xr + (size_t)NTN * HC;
    float* score1= h + (size_t)NTN * HIDC;
    float* score2= score1 + NTN;
    float* zbuf  = score2 + NTN;
    float* pn    = zbuf + NBG * 272;
    int* keep1 = (int*)(pn + 2);
    int* keep2 = keep1 + NTN;
    int* deg   = keep2 + NTN;
    int* off   = deg + NTN;
    int* cur   = off + NTN + 1;
    int* deg2  = cur + NTN;
    int* off2  = deg2 + NTN;
    int* cur2  = off2 + NTN + 1;
    int* esrc  = cur2 + NTN;
    int* esrc2 = esrc + EE;
    float* eaP  = (float*)(esrc2 + EE);
    float* eaP2 = eaP + (size_t)EE * EDIM;

    // ---- CSR layer 1 (all edges) + p-norms ----
    hipMemsetAsync(deg, 0, NTN * sizeof(int), stream);
    prep_pn<<<1, 64, 0, stream>>>(p1, p2, pn);
    edge_hist<<<EE / 256, 256, 0, stream>>>(dstA, srcA, nullptr, deg);
    scan_deg<<<1, 1024, 0, stream>>>(deg, off, cur);
    edge_scatter<<<EE / 256, 256, 0, stream>>>(dstA, srcA, nullptr, ea, cur, esrc, eaP);

    // ---- layer 1 ----
    gemm_node2<FIN><<<NTN / 16, 256, 0, stream>>>(x, W1l, b1l, W1r, b1r, nullptr, xl, xr);
    gat_dst<<<NTN / NPB, 256, 0, stream>>>(xl, xr, eaP, W1e, att1, bias1, p1, pn, esrc, off, h, score1);

    // ---- pool 1 ----
    topk_sel<<<NBG, 512, 0, stream>>>(score1, nullptr, KP1, keep1);

    // ---- CSR layer 2 (live edges only) ----
    hipMemsetAsync(deg2, 0, NTN * sizeof(int), stream);
    edge_hist<<<EE / 256, 256, 0, stream>>>(dstA, srcA, keep1, deg2);
    scan_deg<<<1, 1024, 0, stream>>>(deg2, off2, cur2);
    edge_scatter<<<EE / 256, 256, 0, stream>>>(dstA, srcA, keep1, ea, cur2, esrc2, eaP2);

    // ---- layer 2 (gate of pool1 fused into GEMM staging) ----
    gemm_node2<HIDC><<<NTN / 16, 256, 0, stream>>>(h, W2l, b2l, W2r, b2r, score1, xl, xr);
    gat_dst<<<NTN / NPB, 256, 0, stream>>>(xl, xr, eaP2, W2e, att2, bias2, p2, pn + 1, esrc2, off2, h, score2);

    // ---- pool 2 ----
    topk_sel<<<NBG, 512, 0, stream>>>(score2, keep1, KP2, keep2);

    // ---- global pool (gate2 fused) + MLP ----
    gpool<<<NBG, 512, 0, stream>>>(h, keep2, score2, act, zbuf);
    mlp<<<NBG, 128, 0, stream>>>(zbuf, Wf1, bf1, Wf2, bf2, Wf3, bf3, (float*)d_out);
}